// Round 1
// baseline (669.117 us; speedup 1.0000x reference)
//
#include <hip/hip_runtime.h>
#include <math.h>

#define U_   100000
#define I_   50000
#define NG_  20000
#define D_   64
#define G_   20
#define B_   16384
#define HGE  96     // (D + 2D)/2
#define D2   128
#define D3   192

struct alignas(16) WaveSmem {
    int   sidx[G_];   // 80 B   (offset 0)
    float ie[D_];     // offset 80   (16B aligned)
    float hb[D_];     // offset 336
    float gz0[D_];    // offset 592
    float t1[HGE];    // offset 848
    float tv[16];     // offset 1232
    float sc[G_];     // offset 1296
    float gef[D_];    // offset 1376
};                    // total 1632 B

__global__ __launch_bounds__(256) void vargr_fused_kernel(
    const int*   __restrict__ group_inputs,
    const int*   __restrict__ item_inputs,
    const int*   __restrict__ group_members,
    const float* __restrict__ eps,
    const float* __restrict__ user_emb,
    const float* __restrict__ item_emb,
    const float* __restrict__ ue_w1, const float* __restrict__ ue_b1,
    const float* __restrict__ ue_w2, const float* __restrict__ ue_b2,
    const float* __restrict__ ge_w1, const float* __restrict__ ge_b1,
    const float* __restrict__ ge_w2, const float* __restrict__ ge_b2,
    const float* __restrict__ at_w1, const float* __restrict__ at_b1,
    const float* __restrict__ at_w2, const float* __restrict__ at_b2,
    const float* __restrict__ pr_w1, const float* __restrict__ pr_b1,
    const float* __restrict__ pr_w2, const float* __restrict__ pr_b2,
    float* __restrict__ out, int nb)
{
    __shared__ WaveSmem sm[4];
    const int tid = threadIdx.x;
    const int w   = tid >> 6;   // wave id within block
    const int j   = tid & 63;   // lane id
    const int b   = blockIdx.x * 4 + w;   // batch element (grid exact: nb % 4 == 0)
    WaveSmem& S = sm[w];

    const int gid  = group_inputs[b];
    const int item = item_inputs[b];

    // ---- S0: member indices + item embedding into LDS ----
    if (j < G_) S.sidx[j] = group_members[gid * G_ + j];
    S.ie[j] = item_emb[(size_t)item * D_ + j];

    // W1 column j into registers (reused for all 20 members)
    float w1c[D_];
    #pragma unroll
    for (int k = 0; k < D_; ++k) w1c[k] = ue_w1[k * D_ + j];

    __syncthreads();

    // ---- S1: member MLP layer 1, mean of relu-hidden across members ----
    // mean(enc) = mean(relu(me@W1+b1)) @ W2 + b2  (W2 is linear -> pull mean inside)
    float hsum = 0.f;
    const float b1j = ue_b1[j];
    for (int g = 0; g < G_; ++g) {
        const float* mrow = user_emb + (size_t)S.sidx[g] * D_;
        float acc = b1j;
        #pragma unroll
        for (int kq = 0; kq < D_ / 4; ++kq) {
            const float4 m4 = *reinterpret_cast<const float4*>(mrow + kq * 4);
            acc += m4.x * w1c[kq * 4 + 0];
            acc += m4.y * w1c[kq * 4 + 1];
            acc += m4.z * w1c[kq * 4 + 2];
            acc += m4.w * w1c[kq * 4 + 3];
        }
        hsum += fmaxf(acc, 0.f);
    }
    S.hb[j] = hsum * (1.f / G_);
    __syncthreads();

    // ---- S2: layer 2 (hbar @ W2 + b2), relu -> gz0 ; also item part of attention hidden ----
    {
        float acc = ue_b2[j];
        #pragma unroll
        for (int kq = 0; kq < D_ / 4; ++kq) {
            const float4 h4 = *reinterpret_cast<const float4*>(&S.hb[kq * 4]);
            acc += h4.x * ue_w2[(kq * 4 + 0) * D_ + j];
            acc += h4.y * ue_w2[(kq * 4 + 1) * D_ + j];
            acc += h4.z * ue_w2[(kq * 4 + 2) * D_ + j];
            acc += h4.w * ue_w2[(kq * 4 + 3) * D_ + j];
        }
        S.gz0[j] = fmaxf(acc, 0.f);
    }
    if (j < 16) {
        // tv[u] = at_b1[u] + sum_k ie[k] * at_w1[64+k][u]
        float acc = at_b1[j];
        #pragma unroll 8
        for (int k = 0; k < D_; ++k)
            acc += S.ie[k] * at_w1[(D_ + k) * 16 + j];
        S.tv[j] = acc;
    }
    __syncthreads();

    // ---- S3: group encoder layer 1: t1 = relu(gz0 @ ge_w1 + ge_b1), 96 cols ----
    #pragma unroll
    for (int half = 0; half < 2; ++half) {
        const int jj = j + half * 64;
        if (jj < HGE) {
            float acc = ge_b1[jj];
            #pragma unroll
            for (int kq = 0; kq < D_ / 4; ++kq) {
                const float4 g4 = *reinterpret_cast<const float4*>(&S.gz0[kq * 4]);
                acc += g4.x * ge_w1[(kq * 4 + 0) * HGE + jj];
                acc += g4.y * ge_w1[(kq * 4 + 1) * HGE + jj];
                acc += g4.z * ge_w1[(kq * 4 + 2) * HGE + jj];
                acc += g4.w * ge_w1[(kq * 4 + 3) * HGE + jj];
            }
            S.t1[jj] = fmaxf(acc, 0.f);
        }
    }
    __syncthreads();

    // ---- S4: group encoder layer 2 -> z_mu (col j), z_sigma (col j+64); attention scores ----
    float mu, sig;
    {
        float a0 = ge_b2[j];
        float a1 = ge_b2[j + 64];
        #pragma unroll
        for (int kq = 0; kq < HGE / 4; ++kq) {
            const float4 t4 = *reinterpret_cast<const float4*>(&S.t1[kq * 4]);
            a0 += t4.x * ge_w2[(kq * 4 + 0) * D2 + j];
            a0 += t4.y * ge_w2[(kq * 4 + 1) * D2 + j];
            a0 += t4.z * ge_w2[(kq * 4 + 2) * D2 + j];
            a0 += t4.w * ge_w2[(kq * 4 + 3) * D2 + j];
            a1 += t4.x * ge_w2[(kq * 4 + 0) * D2 + 64 + j];
            a1 += t4.y * ge_w2[(kq * 4 + 1) * D2 + 64 + j];
            a1 += t4.z * ge_w2[(kq * 4 + 2) * D2 + 64 + j];
            a1 += t4.w * ge_w2[(kq * 4 + 3) * D2 + 64 + j];
        }
        mu  = a0;
        sig = 0.1f + 0.9f / (1.f + expf(-a1));
    }
    {
        // 4 members in parallel (16 lanes each), 5 rounds
        const int u = j & 15;
        const int q = j >> 4;
        const float aw2u = at_w2[u];
        #pragma unroll
        for (int gg = 0; gg < 5; ++gg) {
            const int g = q + gg * 4;
            const float* mrow = user_emb + (size_t)S.sidx[g] * D_;
            float hh = S.tv[u];
            #pragma unroll
            for (int kq = 0; kq < D_ / 4; ++kq) {
                const float4 m4 = *reinterpret_cast<const float4*>(mrow + kq * 4);
                hh += m4.x * at_w1[(kq * 4 + 0) * 16 + u];
                hh += m4.y * at_w1[(kq * 4 + 1) * 16 + u];
                hh += m4.z * at_w1[(kq * 4 + 2) * 16 + u];
                hh += m4.w * at_w1[(kq * 4 + 3) * 16 + u];
            }
            float v = fmaxf(hh, 0.f) * aw2u;
            v += __shfl_xor(v, 1, 16);
            v += __shfl_xor(v, 2, 16);
            v += __shfl_xor(v, 4, 16);
            v += __shfl_xor(v, 8, 16);
            if (u == 0) S.sc[g] = v + at_b2[0];
        }
    }
    __syncthreads();

    // ---- S5: softmax over 20 member scores ----
    if (j < 32) {
        const float s = (j < G_) ? S.sc[j] : -INFINITY;
        float m = s;
        #pragma unroll
        for (int off = 16; off; off >>= 1) m = fmaxf(m, __shfl_xor(m, off, 32));
        const float e = (j < G_) ? expf(s - m) : 0.f;
        float sum = e;
        #pragma unroll
        for (int off = 16; off; off >>= 1) sum += __shfl_xor(sum, off, 32);
        if (j < G_) S.sc[j] = e / sum;
    }
    __syncthreads();

    // ---- S6: attention-weighted member sum + reparameterized group embedding ----
    {
        float ga = 0.f;
        #pragma unroll
        for (int g = 0; g < G_; ++g)
            ga += S.sc[g] * user_emb[(size_t)S.sidx[g] * D_ + j];
        const float gef = ga + mu + sig * eps[(size_t)b * D_ + j];
        S.gef[j] = gef;
    }
    __syncthreads();

    // ---- S7: predictor MLP on ncf = [gef*ie, gef, ie] (192) -> 8 -> 1 ----
    {
        const int uu = j & 7;
        const int c  = j >> 3;   // 8 chunks x 24 k
        float part = 0.f;
        #pragma unroll
        for (int kk = 0; kk < 24; ++kk) {
            const int k = c * 24 + kk;
            float x;
            if (k < 64)       x = S.gef[k] * S.ie[k];
            else if (k < 128) x = S.gef[k - 64];
            else              x = S.ie[k - 128];
            part += x * pr_w1[k * 8 + uu];
        }
        part += __shfl_xor(part, 8,  64);
        part += __shfl_xor(part, 16, 64);
        part += __shfl_xor(part, 32, 64);
        float h = fmaxf(part + pr_b1[uu], 0.f) * pr_w2[uu];
        h += __shfl_xor(h, 1, 64);
        h += __shfl_xor(h, 2, 64);
        h += __shfl_xor(h, 4, 64);
        if (j == 0) out[b] = 1.f / (1.f + expf(-(h + pr_b2[0])));
    }
}

extern "C" void kernel_launch(void* const* d_in, const int* in_sizes, int n_in,
                              void* d_out, int out_size, void* d_ws, size_t ws_size,
                              hipStream_t stream) {
    const int*   group_inputs  = (const int*)d_in[0];
    const int*   item_inputs   = (const int*)d_in[1];
    const int*   group_members = (const int*)d_in[2];
    const float* eps           = (const float*)d_in[3];
    const float* user_emb      = (const float*)d_in[4];
    const float* item_emb      = (const float*)d_in[5];
    const float* ue_w1 = (const float*)d_in[6];
    const float* ue_b1 = (const float*)d_in[7];
    const float* ue_w2 = (const float*)d_in[8];
    const float* ue_b2 = (const float*)d_in[9];
    const float* ge_w1 = (const float*)d_in[10];
    const float* ge_b1 = (const float*)d_in[11];
    const float* ge_w2 = (const float*)d_in[12];
    const float* ge_b2 = (const float*)d_in[13];
    const float* at_w1 = (const float*)d_in[14];
    const float* at_b1 = (const float*)d_in[15];
    const float* at_w2 = (const float*)d_in[16];
    const float* at_b2 = (const float*)d_in[17];
    const float* pr_w1 = (const float*)d_in[18];
    const float* pr_b1 = (const float*)d_in[19];
    const float* pr_w2 = (const float*)d_in[20];
    const float* pr_b2 = (const float*)d_in[21];
    float* out = (float*)d_out;

    const int nb = in_sizes[0];          // B = 16384, divisible by 4
    const int grid = nb / 4;

    vargr_fused_kernel<<<grid, 256, 0, stream>>>(
        group_inputs, item_inputs, group_members, eps, user_emb, item_emb,
        ue_w1, ue_b1, ue_w2, ue_b2, ge_w1, ge_b1, ge_w2, ge_b2,
        at_w1, at_b1, at_w2, at_b2, pr_w1, pr_b1, pr_w2, pr_b2,
        out, nb);
}